// Round 1
// baseline (1344.152 us; speedup 1.0000x reference)
//
#include <hip/hip_runtime.h>
#include <math.h>

#define CDIM 128
#define NTOT 4096

// ---------------------------------------------------------------------------
// Generic 1x1-conv projection: Y[b][o][n] = sum_c W[o][c] * X[b][c][n] + bias[o]
// (+ optional residual). X,Y: [4][128][4096]; W: [O=128][128].
// grid (64 n-tiles, 4 batches), block 256.
// ---------------------------------------------------------------------------
__global__ __launch_bounds__(256) void proj_kernel(
    const float* __restrict__ X, const float* __restrict__ W,
    const float* __restrict__ bias, const float* __restrict__ res,
    float* __restrict__ Y)
{
    __shared__ float Xs[CDIM][64];   // 32 KB  [c][n]
    __shared__ float Ws[16][CDIM];   //  8 KB  one 16-row chunk of W

    const int t  = threadIdx.x;
    const int b  = blockIdx.y;
    const int n0 = blockIdx.x * 64;
    const float* Xb = X + (size_t)b * CDIM * NTOT;

    for (int idx = t; idx < CDIM * 64; idx += 256) {
        int c = idx >> 6, n = idx & 63;
        Xs[c][n] = Xb[(size_t)c * NTOT + n0 + n];
    }

    const int n  = t & 63;
    const int og = t >> 6;       // 0..3 (wave-uniform -> Ws reads broadcast)
    const int o0 = og * 4;
    const size_t out_base = (size_t)b * CDIM * NTOT + n0 + n;

    for (int chunk = 0; chunk < 8; ++chunk) {
        const int obase = chunk * 16;
        __syncthreads();  // protect Ws from previous chunk's readers
        for (int idx = t; idx < (16 * CDIM) / 4; idx += 256) {
            ((float4*)Ws)[idx] = ((const float4*)(W + obase * CDIM))[idx];
        }
        __syncthreads();

        float acc0 = bias[obase + o0 + 0];
        float acc1 = bias[obase + o0 + 1];
        float acc2 = bias[obase + o0 + 2];
        float acc3 = bias[obase + o0 + 3];
        for (int c = 0; c < CDIM; c += 4) {
            float x0 = Xs[c + 0][n], x1 = Xs[c + 1][n];
            float x2 = Xs[c + 2][n], x3 = Xs[c + 3][n];
            float4 w0 = *(const float4*)&Ws[o0 + 0][c];
            float4 w1 = *(const float4*)&Ws[o0 + 1][c];
            float4 w2 = *(const float4*)&Ws[o0 + 2][c];
            float4 w3 = *(const float4*)&Ws[o0 + 3][c];
            acc0 = fmaf(w0.x, x0, acc0); acc0 = fmaf(w0.y, x1, acc0);
            acc0 = fmaf(w0.z, x2, acc0); acc0 = fmaf(w0.w, x3, acc0);
            acc1 = fmaf(w1.x, x0, acc1); acc1 = fmaf(w1.y, x1, acc1);
            acc1 = fmaf(w1.z, x2, acc1); acc1 = fmaf(w1.w, x3, acc1);
            acc2 = fmaf(w2.x, x0, acc2); acc2 = fmaf(w2.y, x1, acc2);
            acc2 = fmaf(w2.z, x2, acc2); acc2 = fmaf(w2.w, x3, acc2);
            acc3 = fmaf(w3.x, x0, acc3); acc3 = fmaf(w3.y, x1, acc3);
            acc3 = fmaf(w3.z, x2, acc3); acc3 = fmaf(w3.w, x3, acc3);
        }
        const int o = obase + o0;
        if (res) {
            Y[out_base + (size_t)(o + 0) * NTOT] = acc0 + res[out_base + (size_t)(o + 0) * NTOT];
            Y[out_base + (size_t)(o + 1) * NTOT] = acc1 + res[out_base + (size_t)(o + 1) * NTOT];
            Y[out_base + (size_t)(o + 2) * NTOT] = acc2 + res[out_base + (size_t)(o + 2) * NTOT];
            Y[out_base + (size_t)(o + 3) * NTOT] = acc3 + res[out_base + (size_t)(o + 3) * NTOT];
        } else {
            Y[out_base + (size_t)(o + 0) * NTOT] = acc0;
            Y[out_base + (size_t)(o + 1) * NTOT] = acc1;
            Y[out_base + (size_t)(o + 2) * NTOT] = acc2;
            Y[out_base + (size_t)(o + 3) * NTOT] = acc3;
        }
    }
}

// ---------------------------------------------------------------------------
// Flash-style attention, fp32. q,k,v,ao: [4][128][4096] (c-major).
// ao[b][d][i] = sum_j softmax_j(q[:,i].k[:,j]) * v[d][j]
// grid (128 q-tiles, 4 batches), block 256. QT=32, KT=32.
// ---------------------------------------------------------------------------
__global__ __launch_bounds__(256) void attn_kernel(
    const float* __restrict__ q, const float* __restrict__ k,
    const float* __restrict__ v, float* __restrict__ ao)
{
    __shared__ float Qs[CDIM][32];    // 16 KB   [c][i]
    __shared__ float Ks[CDIM][32];    // 16 KB   [c][j]
    __shared__ float Vs[32][132];     // 16.5 KB [j][d], pad 132 (16B-aligned rows)
    __shared__ float Ps[32][33];      // 4.1 KB  [i][j], pad 33 kills 32-way conflict
    __shared__ float red[32][9];      // partial max/sum, pad 9 (9 coprime 32)
    __shared__ float mrow[32], mnew_s[32], alpha_s[32], lrow[32];

    const int t  = threadIdx.x;
    const int b  = blockIdx.y;
    const int i0 = blockIdx.x * 32;
    const size_t base = (size_t)b * CDIM * NTOT;

    for (int idx = t; idx < CDIM * 32; idx += 256) {
        int c = idx >> 5, i = idx & 31;
        Qs[c][i] = q[base + (size_t)c * NTOT + i0 + i];
    }
    if (t < 32) { mrow[t] = -INFINITY; lrow[t] = 0.f; }

    float acc[16];
    #pragma unroll
    for (int u = 0; u < 16; ++u) acc[u] = 0.f;

    const int i  = t & 31;     // query row (S phase) / output row (PV phase)
    const int jg = t >> 5;     // 0..7: j-group in S phase
    const int d0 = jg * 16;    // d-chunk in PV phase

    __syncthreads();

    for (int j0 = 0; j0 < NTOT; j0 += 32) {
        // --- stage K, V tiles (coalesced global reads) ---
        for (int idx = t; idx < CDIM * 32; idx += 256) {
            int c = idx >> 5, j = idx & 31;
            Ks[c][j] = k[base + (size_t)c * NTOT + j0 + j];
        }
        for (int idx = t; idx < CDIM * 32; idx += 256) {
            int d = idx >> 5, j = idx & 31;
            Vs[j][d] = v[base + (size_t)d * NTOT + j0 + j];
        }
        __syncthreads();

        // --- S = Q^T K : thread computes S[i][jb..jb+3] ---
        const int jb = jg * 4;
        float s0 = 0.f, s1 = 0.f, s2 = 0.f, s3 = 0.f;
        #pragma unroll 4
        for (int c = 0; c < CDIM; ++c) {
            float  qv = Qs[c][i];
            float4 kv = *(const float4*)&Ks[c][jb];
            s0 = fmaf(qv, kv.x, s0); s1 = fmaf(qv, kv.y, s1);
            s2 = fmaf(qv, kv.z, s2); s3 = fmaf(qv, kv.w, s3);
        }

        // --- online softmax: row max ---
        red[i][jg] = fmaxf(fmaxf(s0, s1), fmaxf(s2, s3));
        __syncthreads();
        if (t < 32) {
            float m_old = mrow[t];
            float tmax  = red[t][0];
            #pragma unroll
            for (int g = 1; g < 8; ++g) tmax = fmaxf(tmax, red[t][g]);
            float m_new = fmaxf(m_old, tmax);
            mnew_s[t]  = m_new;
            alpha_s[t] = __expf(m_old - m_new);   // 0 on first tile (m_old=-inf)
            mrow[t]    = m_new;
        }
        __syncthreads();

        // --- P = exp(S - m), row-sum partials ---
        const float m = mnew_s[i];
        float p0 = __expf(s0 - m), p1 = __expf(s1 - m);
        float p2 = __expf(s2 - m), p3 = __expf(s3 - m);
        Ps[i][jb + 0] = p0; Ps[i][jb + 1] = p1;
        Ps[i][jb + 2] = p2; Ps[i][jb + 3] = p3;
        red[i][jg] = p0 + p1 + p2 + p3;
        __syncthreads();

        if (t < 32) {
            float s = 0.f;
            #pragma unroll
            for (int g = 0; g < 8; ++g) s += red[t][g];
            lrow[t] = lrow[t] * alpha_s[t] + s;
        }

        // --- O = O*alpha + P V : thread owns O[i][d0..d0+15] ---
        const float a = alpha_s[i];
        #pragma unroll
        for (int u = 0; u < 16; ++u) acc[u] *= a;
        for (int j = 0; j < 32; ++j) {
            float  p  = Ps[i][j];
            float4 v0 = *(const float4*)&Vs[j][d0 + 0];
            float4 v1 = *(const float4*)&Vs[j][d0 + 4];
            float4 v2 = *(const float4*)&Vs[j][d0 + 8];
            float4 v3 = *(const float4*)&Vs[j][d0 + 12];
            acc[0]  = fmaf(p, v0.x, acc[0]);  acc[1]  = fmaf(p, v0.y, acc[1]);
            acc[2]  = fmaf(p, v0.z, acc[2]);  acc[3]  = fmaf(p, v0.w, acc[3]);
            acc[4]  = fmaf(p, v1.x, acc[4]);  acc[5]  = fmaf(p, v1.y, acc[5]);
            acc[6]  = fmaf(p, v1.z, acc[6]);  acc[7]  = fmaf(p, v1.w, acc[7]);
            acc[8]  = fmaf(p, v2.x, acc[8]);  acc[9]  = fmaf(p, v2.y, acc[9]);
            acc[10] = fmaf(p, v2.z, acc[10]); acc[11] = fmaf(p, v2.w, acc[11]);
            acc[12] = fmaf(p, v3.x, acc[12]); acc[13] = fmaf(p, v3.y, acc[13]);
            acc[14] = fmaf(p, v3.z, acc[14]); acc[15] = fmaf(p, v3.w, acc[15]);
        }
        __syncthreads();  // tiles + red/Ps reusable; also publishes lrow
    }

    const float linv = 1.f / lrow[i];
    #pragma unroll
    for (int u = 0; u < 16; ++u)
        ao[base + (size_t)(d0 + u) * NTOT + i0 + i] = acc[u] * linv;
}

// ---------------------------------------------------------------------------
extern "C" void kernel_launch(void* const* d_in, const int* in_sizes, int n_in,
                              void* d_out, int out_size, void* d_ws, size_t ws_size,
                              hipStream_t stream)
{
    const float* x  = (const float*)d_in[0];
    const float* Wq = (const float*)d_in[1];
    const float* bq = (const float*)d_in[2];
    const float* Wk = (const float*)d_in[3];
    const float* bk = (const float*)d_in[4];
    const float* Wv = (const float*)d_in[5];
    const float* bv = (const float*)d_in[6];
    const float* Wo = (const float*)d_in[7];
    const float* bo = (const float*)d_in[8];
    float* out = (float*)d_out;

    const size_t PER_BUF = (size_t)4 * CDIM * NTOT;  // 2,097,152 floats
    float* q_ws  = (float*)d_ws;
    float* k_ws  = q_ws + PER_BUF;
    float* v_ws  = k_ws + PER_BUF;
    float* ao_ws = v_ws + PER_BUF;

    dim3 pgrid(NTOT / 64, 4);
    dim3 agrid(NTOT / 32, 4);
    dim3 blk(256);

    proj_kernel<<<pgrid, blk, 0, stream>>>(x, Wq, bq, nullptr, q_ws);
    proj_kernel<<<pgrid, blk, 0, stream>>>(x, Wk, bk, nullptr, k_ws);
    proj_kernel<<<pgrid, blk, 0, stream>>>(x, Wv, bv, nullptr, v_ws);
    attn_kernel<<<agrid, blk, 0, stream>>>(q_ws, k_ws, v_ws, ao_ws);
    proj_kernel<<<pgrid, blk, 0, stream>>>(ao_ws, Wo, bo, x, out);
}

// Round 3
// 347.056 us; speedup vs baseline: 3.8730x; 3.8730x over previous
//
#include <hip/hip_runtime.h>
#include <math.h>
#include <stdint.h>

#define CDIM 128
#define NTOT 4096

typedef _Float16 f16x8 __attribute__((ext_vector_type(8)));  // 8 fp16 (4 VGPRs)
typedef float floatx4 __attribute__((ext_vector_type(4)));   // MFMA accumulator

static __device__ __forceinline__ floatx4 mfma16(f16x8 a, f16x8 b, floatx4 c) {
    return __builtin_amdgcn_mfma_f32_16x16x32_f16(a, b, c, 0, 0, 0);
}

// fp32 -> fp16 bits, round-to-nearest-even
static __device__ __forceinline__ unsigned short f2h(float f) {
    _Float16 h = (_Float16)f;
    return __builtin_bit_cast(unsigned short, h);
}

static __device__ __forceinline__ float redmax16(float v) {
    v = fmaxf(v, __shfl_xor(v, 1, 16));
    v = fmaxf(v, __shfl_xor(v, 2, 16));
    v = fmaxf(v, __shfl_xor(v, 4, 16));
    v = fmaxf(v, __shfl_xor(v, 8, 16));
    return v;
}
static __device__ __forceinline__ float redsum16(float v) {
    v += __shfl_xor(v, 1, 16);
    v += __shfl_xor(v, 2, 16);
    v += __shfl_xor(v, 4, 16);
    v += __shfl_xor(v, 8, 16);
    return v;
}

// ---------------------------------------------------------------------------
// Fused q/k/v projection. x: [4][128][4096] fp32. Outputs fp16:
//   qo, ko: [b][n][c]  (n-major, MFMA A/B-friendly)
//   vo:     [b][c][n]  (c-major, PV B-operand friendly)
// grid (64, 4), 256 threads. Register-blocked 4n x 4o per thread.
// ---------------------------------------------------------------------------
__global__ __launch_bounds__(256) void qkv_proj_kernel(
    const float* __restrict__ x,
    const float* __restrict__ Wq, const float* __restrict__ bq,
    const float* __restrict__ Wk, const float* __restrict__ bk,
    const float* __restrict__ Wv, const float* __restrict__ bv,
    unsigned short* __restrict__ qo, unsigned short* __restrict__ ko,
    unsigned short* __restrict__ vo)
{
    __shared__ __align__(16) float Xs[CDIM][68];    // [c][n] pad 68
    __shared__ __align__(16) float Ws[CDIM][132];   // [o][c] pad 132

    const int t = threadIdx.x, b = blockIdx.y, n0 = blockIdx.x * 64;

    for (int i = 0; i < 8; ++i) {
        int idx = t + i * 256; int c = idx >> 4, n4 = idx & 15;
        *(float4*)&Xs[c][n4 * 4] =
            *(const float4*)&x[((size_t)b * CDIM + c) * NTOT + n0 + n4 * 4];
    }

    const int tn = t & 15, to = t >> 4;

    for (int s = 0; s < 3; ++s) {
        const float* W    = (s == 0) ? Wq : (s == 1) ? Wk : Wv;
        const float* bias = (s == 0) ? bq : (s == 1) ? bk : bv;
        __syncthreads();   // prev readers of Ws done (also covers Xs staging, iter 0)
        for (int i = 0; i < 16; ++i) {
            int idx = t + i * 256; int o = idx >> 5, c4 = idx & 31;
            *(float4*)&Ws[o][c4 * 4] = *(const float4*)&W[o * CDIM + c4 * 4];
        }
        __syncthreads();

        for (int pass = 0; pass < 2; ++pass) {
            const int ob = pass * 64 + to * 4;
            float acc[4][4];   // [oi][ni]
            #pragma unroll
            for (int oi = 0; oi < 4; ++oi) {
                float bv_ = bias[ob + oi];
                #pragma unroll
                for (int ni = 0; ni < 4; ++ni) acc[oi][ni] = bv_;
            }
            for (int c4 = 0; c4 < 32; ++c4) {
                float4 wv[4];
                #pragma unroll
                for (int oi = 0; oi < 4; ++oi) wv[oi] = *(const float4*)&Ws[ob + oi][c4 * 4];
                #pragma unroll
                for (int cc = 0; cc < 4; ++cc) {
                    float4 xv = *(const float4*)&Xs[c4 * 4 + cc][tn * 4];
                    #pragma unroll
                    for (int oi = 0; oi < 4; ++oi) {
                        float wsc = (cc == 0) ? wv[oi].x : (cc == 1) ? wv[oi].y
                                  : (cc == 2) ? wv[oi].z : wv[oi].w;
                        acc[oi][0] = fmaf(xv.x, wsc, acc[oi][0]);
                        acc[oi][1] = fmaf(xv.y, wsc, acc[oi][1]);
                        acc[oi][2] = fmaf(xv.z, wsc, acc[oi][2]);
                        acc[oi][3] = fmaf(xv.w, wsc, acc[oi][3]);
                    }
                }
            }
            if (s < 2) {   // q, k -> [b][n][c] fp16
                unsigned short* dst = (s == 0) ? qo : ko;
                #pragma unroll
                for (int ni = 0; ni < 4; ++ni) {
                    ushort4 u;
                    u.x = f2h(acc[0][ni]); u.y = f2h(acc[1][ni]);
                    u.z = f2h(acc[2][ni]); u.w = f2h(acc[3][ni]);
                    *(ushort4*)&dst[((size_t)b * NTOT + n0 + tn * 4 + ni) * CDIM + ob] = u;
                }
            } else {       // v -> [b][c][n] fp16
                #pragma unroll
                for (int oi = 0; oi < 4; ++oi) {
                    ushort4 u;
                    u.x = f2h(acc[oi][0]); u.y = f2h(acc[oi][1]);
                    u.z = f2h(acc[oi][2]); u.w = f2h(acc[oi][3]);
                    *(ushort4*)&vo[((size_t)b * CDIM + ob + oi) * NTOT + n0 + tn * 4] = u;
                }
            }
        }
    }
}

// ---------------------------------------------------------------------------
// Flash attention with fp16 MFMA (16x16x32). BQ=32 queries/block, KT=64.
// q,k: [b][n][128] fp16; v: [b][128][n] fp16; og: [b][n][128] fp32.
// 256 threads / 4 waves. Wave w: S cols w*16..w*16+15; PV d-cols w*32..w*32+31.
// grid (128, 4).
// ---------------------------------------------------------------------------
__global__ __launch_bounds__(256) void attn_mfma_kernel(
    const unsigned short* __restrict__ qg,
    const unsigned short* __restrict__ kg,
    const unsigned short* __restrict__ vg,
    float* __restrict__ og)
{
    // rows padded: stride 136 ush (272 B: 16B-aligned, 4-word bank stagger); 72 ush (144 B)
    __shared__ __align__(16) unsigned short Qs[32 * 136];
    __shared__ __align__(16) unsigned short Ks[64 * 136];
    __shared__ __align__(16) unsigned short Vs[128 * 72];
    __shared__ __align__(16) unsigned short Ps[32 * 72];
    __shared__ __align__(16) float red_max[32][4];
    __shared__ __align__(16) float red_sum[32][4];
    __shared__ __align__(16) float m_run[32];
    __shared__ __align__(16) float alpha_sh[32];
    __shared__ __align__(16) float l_run[32];

    const int t = threadIdx.x;
    const int w = t >> 6, quad = (t >> 4) & 3, l15 = t & 15;
    const int b = blockIdx.y;
    const int i0 = blockIdx.x * 32;
    const size_t qbase = ((size_t)b * NTOT + i0) * CDIM;   // fp16 elems
    const size_t vbase = (size_t)b * CDIM * NTOT;

    // stage Q (32x128 fp16) once
    {
        int row = t >> 4, col = l15 * 8;
        *(uint4*)&Qs[row * 136 + col]        = *(const uint4*)&qg[qbase + (size_t)row * CDIM + col];
        *(uint4*)&Qs[(row + 16) * 136 + col] = *(const uint4*)&qg[qbase + (size_t)(row + 16) * CDIM + col];
    }
    if (t < 32) {
        m_run[t] = -INFINITY; l_run[t] = 0.f; alpha_sh[t] = 1.f;
        red_sum[t][0] = red_sum[t][1] = red_sum[t][2] = red_sum[t][3] = 0.f;
    }
    __syncthreads();

    // preload Q A-fragments: A[m=l15][k=quad*8+jj], k-chunk f*32
    f16x8 aQ[2][4];
    #pragma unroll
    for (int it = 0; it < 2; ++it)
        #pragma unroll
        for (int f = 0; f < 4; ++f)
            aQ[it][f] = *(const f16x8*)&Qs[(it * 16 + l15) * 136 + f * 32 + quad * 8];

    floatx4 accO[2][2];
    #pragma unroll
    for (int it = 0; it < 2; ++it)
        #pragma unroll
        for (int dt = 0; dt < 2; ++dt)
            accO[it][dt] = (floatx4){0.f, 0.f, 0.f, 0.f};

    for (int j0 = 0; j0 < NTOT; j0 += 64) {
        __syncthreads();   // (A) prev PV reads of Ks/Vs/Ps done; red_sum/alpha final

        // stage K tile (64x128) from [n][c] fp16 (contiguous 16 KB)
        {
            const size_t kb_ = ((size_t)b * NTOT + j0) * CDIM;
            int row = t >> 4, col = l15 * 8;
            #pragma unroll
            for (int it = 0; it < 4; ++it)
                *(uint4*)&Ks[(it * 16 + row) * 136 + col] =
                    *(const uint4*)&kg[kb_ + (size_t)(it * 16 + row) * CDIM + col];
        }
        // stage V tile (128 d x 64 j) from [c][n] fp16
        {
            int dr = t >> 3, ch = (t & 7) * 8;
            #pragma unroll
            for (int it = 0; it < 4; ++it)
                *(uint4*)&Vs[(it * 32 + dr) * 72 + ch] =
                    *(const uint4*)&vg[vbase + (size_t)(it * 32 + dr) * NTOT + j0 + ch];
        }
        if (t < 32)   // fold previous tile's softmax mass
            l_run[t] = l_run[t] * alpha_sh[t] +
                       (red_sum[t][0] + red_sum[t][1] + red_sum[t][2] + red_sum[t][3]);
        __syncthreads();   // (B)

        // --- S = Q^T K for this wave's 16-col stripe ---
        floatx4 accS[2];
        accS[0] = (floatx4){0.f, 0.f, 0.f, 0.f};
        accS[1] = (floatx4){0.f, 0.f, 0.f, 0.f};
        #pragma unroll
        for (int f = 0; f < 4; ++f) {
            f16x8 bK = *(const f16x8*)&Ks[(w * 16 + l15) * 136 + f * 32 + quad * 8];
            accS[0] = mfma16(aQ[0][f], bK, accS[0]);
            accS[1] = mfma16(aQ[1][f], bK, accS[1]);
        }

        // --- per-wave partial row max (16 cols) ---
        #pragma unroll
        for (int it = 0; it < 2; ++it)
            #pragma unroll
            for (int r = 0; r < 4; ++r) {
                float vmx = redmax16(accS[it][r]);
                if (l15 == 0) red_max[it * 16 + quad * 4 + r][w] = vmx;
            }
        __syncthreads();   // (C)

        // --- stats (computed redundantly by every wave), exp, P, rescale ---
        float mn_s[2][4], al_s[2][4], ps_s[2][4];
        #pragma unroll
        for (int it = 0; it < 2; ++it) {
            float4 mo4 = *(const float4*)&m_run[it * 16 + quad * 4];
            #pragma unroll
            for (int r = 0; r < 4; ++r) {
                const int row = it * 16 + quad * 4 + r;
                float4 rm = *(const float4*)&red_max[row][0];
                float mt = fmaxf(fmaxf(rm.x, rm.y), fmaxf(rm.z, rm.w));
                float mo = (r == 0) ? mo4.x : (r == 1) ? mo4.y : (r == 2) ? mo4.z : mo4.w;
                float mn = fmaxf(mo, mt);
                float al = __expf(mo - mn);            // 0 on first tile
                float p  = __expf(accS[it][r] - mn);
                ps_s[it][r] = redsum16(p);
                mn_s[it][r] = mn;
                al_s[it][r] = al;
                Ps[row * 72 + w * 16 + l15] = f2h(p);
                accO[it][0][r] *= al;
                accO[it][1][r] *= al;
            }
        }
        __syncthreads();   // (D) Ps visible

        // stat writeback (read again only after syncs A/B of next iter)
        if (l15 == 0) {
            #pragma unroll
            for (int it = 0; it < 2; ++it)
                #pragma unroll
                for (int r = 0; r < 4; ++r) {
                    const int row = it * 16 + quad * 4 + r;
                    red_sum[row][w] = ps_s[it][r];
                    if (w == 0) { m_run[row] = mn_s[it][r]; alpha_sh[row] = al_s[it][r]; }
                }
        }

        // --- O += P V  (wave's 32-d stripe) ---
        #pragma unroll
        for (int kb = 0; kb < 2; ++kb) {
            f16x8 aP0 = *(const f16x8*)&Ps[l15 * 72 + kb * 32 + quad * 8];
            f16x8 aP1 = *(const f16x8*)&Ps[(16 + l15) * 72 + kb * 32 + quad * 8];
            f16x8 bV0 = *(const f16x8*)&Vs[(w * 32 + l15) * 72 + kb * 32 + quad * 8];
            f16x8 bV1 = *(const f16x8*)&Vs[(w * 32 + 16 + l15) * 72 + kb * 32 + quad * 8];
            accO[0][0] = mfma16(aP0, bV0, accO[0][0]);
            accO[0][1] = mfma16(aP0, bV1, accO[0][1]);
            accO[1][0] = mfma16(aP1, bV0, accO[1][0]);
            accO[1][1] = mfma16(aP1, bV1, accO[1][1]);
        }
    }

    __syncthreads();   // last tile's red_sum/alpha_sh visible

    #pragma unroll
    for (int it = 0; it < 2; ++it)
        #pragma unroll
        for (int r = 0; r < 4; ++r) {
            const int row = it * 16 + quad * 4 + r;
            float lf = l_run[row] * alpha_sh[row] +
                       red_sum[row][0] + red_sum[row][1] + red_sum[row][2] + red_sum[row][3];
            float inv = 1.0f / lf;
            const size_t ob = ((size_t)b * NTOT + i0 + row) * CDIM + w * 32 + l15;
            og[ob]      = accO[it][0][r] * inv;
            og[ob + 16] = accO[it][1][r] * inv;
        }
}

// ---------------------------------------------------------------------------
// Output projection + residual. ao: [b][n][128] fp32 (attn output),
// out[b][o][n] = sum_c Wo[o][c] * ao[n][c] + bo[o] + x[b][o][n]
// grid (64, 4), 256 threads, register-blocked 4n x 4o (dot-product style).
// ---------------------------------------------------------------------------
__global__ __launch_bounds__(256) void out_proj_kernel(
    const float* __restrict__ ao, const float* __restrict__ W,
    const float* __restrict__ bias, const float* __restrict__ res,
    float* __restrict__ out)
{
    __shared__ __align__(16) float XsT[64][132];   // [n][c] pad 132
    __shared__ __align__(16) float Ws[CDIM][132];  // [o][c]

    const int t = threadIdx.x, b = blockIdx.y, n0 = blockIdx.x * 64;

    for (int i = 0; i < 8; ++i) {   // XsT direct copy (no transpose)
        int idx = t + i * 256; int n = idx >> 5, c4 = idx & 31;
        *(float4*)&XsT[n][c4 * 4] =
            *(const float4*)&ao[((size_t)b * NTOT + n0 + n) * CDIM + c4 * 4];
    }
    for (int i = 0; i < 16; ++i) {
        int idx = t + i * 256; int o = idx >> 5, c4 = idx & 31;
        *(float4*)&Ws[o][c4 * 4] = *(const float4*)&W[o * CDIM + c4 * 4];
    }
    __syncthreads();

    const int tn = t & 15, to = t >> 4;
    for (int pass = 0; pass < 2; ++pass) {
        const int ob = pass * 64 + to * 4;
        float acc[4][4];   // [oi][ni], n = tn + ni*16
        #pragma unroll
        for (int oi = 0; oi < 4; ++oi) {
            float bv_ = bias[ob + oi];
            #pragma unroll
            for (int ni = 0; ni < 4; ++ni) acc[oi][ni] = bv_;
        }
        for (int c4 = 0; c4 < 32; ++c4) {
            float4 wv[4], xv[4];
            #pragma unroll
            for (int oi = 0; oi < 4; ++oi) wv[oi] = *(const float4*)&Ws[ob + oi][c4 * 4];
            #pragma unroll
            for (int ni = 0; ni < 4; ++ni) xv[ni] = *(const float4*)&XsT[tn + ni * 16][c4 * 4];
            #pragma unroll
            for (int oi = 0; oi < 4; ++oi)
                #pragma unroll
                for (int ni = 0; ni < 4; ++ni) {
                    acc[oi][ni] = fmaf(xv[ni].x, wv[oi].x, acc[oi][ni]);
                    acc[oi][ni] = fmaf(xv[ni].y, wv[oi].y, acc[oi][ni]);
                    acc[oi][ni] = fmaf(xv[ni].z, wv[oi].z, acc[oi][ni]);
                    acc[oi][ni] = fmaf(xv[ni].w, wv[oi].w, acc[oi][ni]);
                }
        }
        #pragma unroll
        for (int oi = 0; oi < 4; ++oi)
            #pragma unroll
            for (int ni = 0; ni < 4; ++ni) {
                size_t idx = ((size_t)b * CDIM + ob + oi) * NTOT + n0 + tn + ni * 16;
                out[idx] = acc[oi][ni] + res[idx];
            }
    }
}

// ---------------------------------------------------------------------------
extern "C" void kernel_launch(void* const* d_in, const int* in_sizes, int n_in,
                              void* d_out, int out_size, void* d_ws, size_t ws_size,
                              hipStream_t stream)
{
    const float* x  = (const float*)d_in[0];
    const float* Wq = (const float*)d_in[1];
    const float* bq = (const float*)d_in[2];
    const float* Wk = (const float*)d_in[3];
    const float* bk = (const float*)d_in[4];
    const float* Wv = (const float*)d_in[5];
    const float* bv = (const float*)d_in[6];
    const float* Wo = (const float*)d_in[7];
    const float* bo = (const float*)d_in[8];
    float* out = (float*)d_out;

    const size_t PER = (size_t)4 * CDIM * NTOT;   // 2,097,152 elements
    unsigned short* q_ws = (unsigned short*)d_ws;
    unsigned short* k_ws = q_ws + PER;
    unsigned short* v_ws = k_ws + PER;
    float*          ao_ws = (float*)(v_ws + PER);  // fp32 [b][n][c]

    dim3 blk(256);
    qkv_proj_kernel<<<dim3(NTOT / 64, 4), blk, 0, stream>>>(
        x, Wq, bq, Wk, bk, Wv, bv, q_ws, k_ws, v_ws);
    attn_mfma_kernel<<<dim3(NTOT / 32, 4), blk, 0, stream>>>(q_ws, k_ws, v_ws, ao_ws);
    out_proj_kernel<<<dim3(NTOT / 64, 4), blk, 0, stream>>>(ao_ws, Wo, bo, x, out);
}

// Round 4
// 182.967 us; speedup vs baseline: 7.3464x; 1.8968x over previous
//
#include <hip/hip_runtime.h>
#include <math.h>
#include <stdint.h>

#define CDIM 128
#define NTOT 4096

typedef _Float16 f16x8 __attribute__((ext_vector_type(8)));  // 8 fp16 (4 VGPRs)
typedef float floatx4 __attribute__((ext_vector_type(4)));   // MFMA accumulator

static __device__ __forceinline__ floatx4 mfma16(f16x8 a, f16x8 b, floatx4 c) {
    return __builtin_amdgcn_mfma_f32_16x16x32_f16(a, b, c, 0, 0, 0);
}
static __device__ __forceinline__ unsigned short f2h(float f) {
    _Float16 h = (_Float16)f;
    return __builtin_bit_cast(unsigned short, h);
}

// ---------------------------------------------------------------------------
// Fused q/k/v projection, MFMA. x: [4][128][4096] fp32.
// Outputs fp16: qo, ko: [b][n][c]; vo: [b][c][n].
// grid (64 n-tiles, 4 batches, 2 o-halves), 256 threads / 4 waves.
// Wave w owns n-subtile w*16..+15. q,k: C[o][n] = W·X. v: C'[n][o] = X^T·W^T
// (same fragment reads, swapped MFMA operands -> coalesced [c][n] stores).
// ---------------------------------------------------------------------------
__global__ __launch_bounds__(256) void qkv_proj_kernel(
    const float* __restrict__ x,
    const float* __restrict__ Wq, const float* __restrict__ bq,
    const float* __restrict__ Wk, const float* __restrict__ bk,
    const float* __restrict__ Wv, const float* __restrict__ bv,
    unsigned short* __restrict__ qo, unsigned short* __restrict__ ko,
    unsigned short* __restrict__ vo)
{
    __shared__ __align__(16) float          Xs32[CDIM][68];  // 34.8 KB [c][n]
    __shared__ __align__(16) unsigned short Xs[64][136];     // 17.4 KB [n][c] fp16
    __shared__ __align__(16) unsigned short Ws[64][136];     // 17.4 KB [o-half][c] fp16

    const int t = threadIdx.x, b = blockIdx.y, n0 = blockIdx.x * 64;
    const int zo = blockIdx.z * 64;
    const int w = t >> 6, quad = (t >> 4) & 3, l15 = t & 15;

    // phase 1: stage x tile [c][n] fp32 (coalesced along n)
    {
        int c = t >> 1, nh = (t & 1) * 32;
        #pragma unroll
        for (int i = 0; i < 8; ++i)
            *(float4*)&Xs32[c][nh + i * 4] =
                *(const float4*)&x[((size_t)b * CDIM + c) * NTOT + n0 + nh + i * 4];
    }
    __syncthreads();
    // phase 2: transpose -> Xs [n][c] fp16
    {
        int n = t >> 2, ch = (t & 3) * 32;
        #pragma unroll
        for (int i = 0; i < 8; ++i) {
            ushort4 u;
            u.x = f2h(Xs32[ch + i * 4 + 0][n]);
            u.y = f2h(Xs32[ch + i * 4 + 1][n]);
            u.z = f2h(Xs32[ch + i * 4 + 2][n]);
            u.w = f2h(Xs32[ch + i * 4 + 3][n]);
            *(ushort4*)&Xs[n][ch + i * 4] = u;
        }
    }
    __syncthreads();

    // X fragments: lane row n = w*16+l15, k-chunk f*32+quad*8
    f16x8 xf[4];
    #pragma unroll
    for (int f = 0; f < 4; ++f)
        xf[f] = *(const f16x8*)&Xs[w * 16 + l15][f * 32 + quad * 8];

    for (int s = 0; s < 3; ++s) {
        const float* W    = (s == 0) ? Wq : (s == 1) ? Wk : Wv;
        const float* bias = (s == 0) ? bq : (s == 1) ? bk : bv;
        __syncthreads();   // previous Ws readers done
        {
            int o = t >> 2, ch = (t & 3) * 32;
            #pragma unroll
            for (int i = 0; i < 8; ++i) {
                float4 f4 = *(const float4*)&W[(size_t)(zo + o) * CDIM + ch + i * 4];
                ushort4 u = { f2h(f4.x), f2h(f4.y), f2h(f4.z), f2h(f4.w) };
                *(ushort4*)&Ws[o][ch + i * 4] = u;
            }
        }
        __syncthreads();

        if (s < 2) {   // q, k: C[o][n], A = W, B = X
            unsigned short* dst = (s == 0) ? qo : ko;
            #pragma unroll
            for (int ot = 0; ot < 4; ++ot) {
                floatx4 acc = (floatx4){0.f, 0.f, 0.f, 0.f};
                #pragma unroll
                for (int f = 0; f < 4; ++f) {
                    f16x8 aW = *(const f16x8*)&Ws[ot * 16 + l15][f * 32 + quad * 8];
                    acc = mfma16(aW, xf[f], acc);
                }
                const int ob = zo + ot * 16 + quad * 4;
                ushort4 u;
                u.x = f2h(acc[0] + bias[ob + 0]);
                u.y = f2h(acc[1] + bias[ob + 1]);
                u.z = f2h(acc[2] + bias[ob + 2]);
                u.w = f2h(acc[3] + bias[ob + 3]);
                *(ushort4*)&dst[((size_t)b * NTOT + n0 + w * 16 + l15) * CDIM + ob] = u;
            }
        } else {       // v: C'[n][o], A = X, B = W
            #pragma unroll
            for (int ot = 0; ot < 4; ++ot) {
                floatx4 acc = (floatx4){0.f, 0.f, 0.f, 0.f};
                #pragma unroll
                for (int f = 0; f < 4; ++f) {
                    f16x8 bW = *(const f16x8*)&Ws[ot * 16 + l15][f * 32 + quad * 8];
                    acc = mfma16(xf[f], bW, acc);
                }
                const int o = zo + ot * 16 + l15;
                const float bv_ = bias[o];
                ushort4 u;
                u.x = f2h(acc[0] + bv_); u.y = f2h(acc[1] + bv_);
                u.z = f2h(acc[2] + bv_); u.w = f2h(acc[3] + bv_);
                *(ushort4*)&vo[((size_t)b * CDIM + o) * NTOT + n0 + w * 16 + quad * 4] = u;
            }
        }
    }
}

// ---------------------------------------------------------------------------
// Flash attention, transposed softmax. q,k: [b][n][128] fp16; v: [b][128][n]
// fp16; ao: [b][n][128] fp16. grid (64, 4), 256 threads / 4 waves.
// BQ=64 (wave w owns i = w*16+l15), KT=128, 32 iterations.
// T^T = K·Q^T (C cols = queries = lanes) -> softmax stats are in-lane folds +
// 2 cross-lane shuffles; P^T stays wave-private; O^T = V^T·P^T.
// ---------------------------------------------------------------------------
__global__ __launch_bounds__(256) void attn_kernel(
    const unsigned short* __restrict__ qg,
    const unsigned short* __restrict__ kg,
    const unsigned short* __restrict__ vg,
    unsigned short* __restrict__ aog)
{
    __shared__ __align__(16) unsigned short Ks[128 * 136];   // [j][c] 34.8 KB
    __shared__ __align__(16) unsigned short Vs[128 * 136];   // [d][j] 34.8 KB
    __shared__ __align__(16) unsigned short Ps[4][16 * 136]; // per-wave [i][j] 17.4 KB

    const int t = threadIdx.x;
    const int w = t >> 6, quad = (t >> 4) & 3, l15 = t & 15;
    const int b = blockIdx.y;
    const int i0 = blockIdx.x * 64;
    const size_t vbase = (size_t)b * CDIM * NTOT;

    // Q B-fragments direct from global: B[k=c][n=i], i = w*16+l15
    f16x8 bQ[4];
    {
        const size_t qrow = ((size_t)b * NTOT + i0 + w * 16 + l15) * CDIM;
        #pragma unroll
        for (int f = 0; f < 4; ++f)
            bQ[f] = *(const f16x8*)&qg[qrow + f * 32 + quad * 8];
    }

    floatx4 accO[8];
    #pragma unroll
    for (int dt = 0; dt < 8; ++dt) accO[dt] = (floatx4){0.f, 0.f, 0.f, 0.f};
    float m_run = -INFINITY, l_part = 0.f;

    for (int j0 = 0; j0 < NTOT; j0 += 128) {
        __syncthreads();   // (A) all waves done reading Ks/Vs of previous tile

        // stage K tile [j 128][c 128] and V tile [d 128][j 128]
        {
            const size_t kb_ = ((size_t)b * NTOT + j0) * CDIM;
            #pragma unroll
            for (int r = 0; r < 8; ++r) {
                int flat = r * 256 + t;
                int row = flat >> 4, c16 = (flat & 15) * 8;
                *(uint4*)&Ks[row * 136 + c16] =
                    *(const uint4*)&kg[kb_ + (size_t)row * CDIM + c16];
                *(uint4*)&Vs[row * 136 + c16] =
                    *(const uint4*)&vg[vbase + (size_t)row * NTOT + j0 + c16];
            }
        }
        __syncthreads();   // (B) tiles ready

        // --- T^T[j][i] = K·Q^T : 8 j-tiles ---
        floatx4 accT[8];
        #pragma unroll
        for (int jt = 0; jt < 8; ++jt) {
            accT[jt] = (floatx4){0.f, 0.f, 0.f, 0.f};
            #pragma unroll
            for (int f = 0; f < 4; ++f) {
                f16x8 aK = *(const f16x8*)&Ks[(jt * 16 + l15) * 136 + f * 32 + quad * 8];
                accT[jt] = mfma16(aK, bQ[f], accT[jt]);
            }
        }

        // --- online softmax (all per-lane; lane = one query) ---
        float tm = accT[0][0];
        #pragma unroll
        for (int jt = 0; jt < 8; ++jt)
            #pragma unroll
            for (int r = 0; r < 4; ++r) tm = fmaxf(tm, accT[jt][r]);
        tm = fmaxf(tm, __shfl_xor(tm, 16));   // reduce across quads
        tm = fmaxf(tm, __shfl_xor(tm, 32));
        const float m_new = fmaxf(m_run, tm);
        const float alpha = __expf(m_run - m_new);   // 0 on first tile
        m_run = m_new;

        float psum = 0.f;
        #pragma unroll
        for (int jt = 0; jt < 8; ++jt) {
            float p0 = __expf(accT[jt][0] - m_new);
            float p1 = __expf(accT[jt][1] - m_new);
            float p2 = __expf(accT[jt][2] - m_new);
            float p3 = __expf(accT[jt][3] - m_new);
            psum += (p0 + p1) + (p2 + p3);
            ushort4 u = { f2h(p0), f2h(p1), f2h(p2), f2h(p3) };
            *(ushort4*)&Ps[w][l15 * 136 + jt * 16 + quad * 4] = u;  // [i][j]
        }
        l_part = l_part * alpha + psum;
        #pragma unroll
        for (int dt = 0; dt < 8; ++dt) {
            accO[dt][0] *= alpha; accO[dt][1] *= alpha;
            accO[dt][2] *= alpha; accO[dt][3] *= alpha;
        }

        // --- O^T += V^T·P^T (wave-private P; lgkmcnt wait only) ---
        f16x8 bP[4];
        #pragma unroll
        for (int kb = 0; kb < 4; ++kb)
            bP[kb] = *(const f16x8*)&Ps[w][l15 * 136 + kb * 32 + quad * 8];
        #pragma unroll
        for (int dt = 0; dt < 8; ++dt)
            #pragma unroll
            for (int kb = 0; kb < 4; ++kb) {
                f16x8 aV = *(const f16x8*)&Vs[(dt * 16 + l15) * 136 + kb * 32 + quad * 8];
                accO[dt] = mfma16(aV, bP[kb], accO[dt]);
            }
    }

    // final l reduction + store O^T[d][i] as ao[b][i][d] fp16
    float lf = l_part;
    lf += __shfl_xor(lf, 16);
    lf += __shfl_xor(lf, 32);
    const float inv = 1.0f / lf;
    const size_t orow = ((size_t)b * NTOT + i0 + w * 16 + l15) * CDIM;
    #pragma unroll
    for (int dt = 0; dt < 8; ++dt) {
        ushort4 u;
        u.x = f2h(accO[dt][0] * inv); u.y = f2h(accO[dt][1] * inv);
        u.z = f2h(accO[dt][2] * inv); u.w = f2h(accO[dt][3] * inv);
        *(ushort4*)&aog[orow + dt * 16 + quad * 4] = u;
    }
}

// ---------------------------------------------------------------------------
// Output projection + residual, MFMA. ao: [b][n][128] fp16.
// out[b][o][n] = Wo·ao^T + bo + x. grid (64, 4, 2 o-halves), 256 threads.
// ---------------------------------------------------------------------------
__global__ __launch_bounds__(256) void out_proj_kernel(
    const unsigned short* __restrict__ ao,
    const float* __restrict__ Wo, const float* __restrict__ bo,
    const float* __restrict__ x, float* __restrict__ out)
{
    __shared__ __align__(16) unsigned short As[64][136];  // [n][c]
    __shared__ __align__(16) unsigned short Ws[64][136];  // [o-half][c]

    const int t = threadIdx.x, b = blockIdx.y, n0 = blockIdx.x * 64;
    const int zo = blockIdx.z * 64;
    const int w = t >> 6, quad = (t >> 4) & 3, l15 = t & 15;

    #pragma unroll
    for (int r = 0; r < 4; ++r) {   // stage ao tile (direct fp16 copy)
        int flat = r * 256 + t;
        int row = flat >> 4, c16 = (flat & 15) * 8;
        *(uint4*)&As[row][c16] =
            *(const uint4*)&ao[((size_t)b * NTOT + n0 + row) * CDIM + c16];
    }
    {
        int o = t >> 2, ch = (t & 3) * 32;
        #pragma unroll
        for (int i = 0; i < 8; ++i) {
            float4 f4 = *(const float4*)&Wo[(size_t)(zo + o) * CDIM + ch + i * 4];
            ushort4 u = { f2h(f4.x), f2h(f4.y), f2h(f4.z), f2h(f4.w) };
            *(ushort4*)&Ws[o][ch + i * 4] = u;
        }
    }
    __syncthreads();

    f16x8 bA[4];
    #pragma unroll
    for (int f = 0; f < 4; ++f)
        bA[f] = *(const f16x8*)&As[w * 16 + l15][f * 32 + quad * 8];

    #pragma unroll
    for (int ot = 0; ot < 4; ++ot) {
        floatx4 acc = (floatx4){0.f, 0.f, 0.f, 0.f};
        #pragma unroll
        for (int f = 0; f < 4; ++f) {
            f16x8 aW = *(const f16x8*)&Ws[ot * 16 + l15][f * 32 + quad * 8];
            acc = mfma16(aW, bA[f], acc);
        }
        const int ob = zo + ot * 16 + quad * 4;
        #pragma unroll
        for (int r = 0; r < 4; ++r) {
            size_t idx = ((size_t)b * CDIM + ob + r) * NTOT + n0 + w * 16 + l15;
            out[idx] = acc[r] + bo[ob + r] + x[idx];
        }
    }
}

// ---------------------------------------------------------------------------
extern "C" void kernel_launch(void* const* d_in, const int* in_sizes, int n_in,
                              void* d_out, int out_size, void* d_ws, size_t ws_size,
                              hipStream_t stream)
{
    const float* x  = (const float*)d_in[0];
    const float* Wq = (const float*)d_in[1];
    const float* bq = (const float*)d_in[2];
    const float* Wk = (const float*)d_in[3];
    const float* bk = (const float*)d_in[4];
    const float* Wv = (const float*)d_in[5];
    const float* bv = (const float*)d_in[6];
    const float* Wo = (const float*)d_in[7];
    const float* bo = (const float*)d_in[8];
    float* out = (float*)d_out;

    const size_t PER = (size_t)4 * CDIM * NTOT;   // 2,097,152 elements
    unsigned short* q_ws  = (unsigned short*)d_ws;
    unsigned short* k_ws  = q_ws + PER;
    unsigned short* v_ws  = k_ws + PER;
    unsigned short* ao_ws = v_ws + PER;           // fp16 [b][n][c]

    dim3 blk(256);
    qkv_proj_kernel<<<dim3(64, 4, 2), blk, 0, stream>>>(
        x, Wq, bq, Wk, bk, Wv, bv, q_ws, k_ws, v_ws);
    attn_kernel<<<dim3(64, 4), blk, 0, stream>>>(q_ws, k_ws, v_ws, ao_ws);
    out_proj_kernel<<<dim3(64, 4, 2), blk, 0, stream>>>(ao_ws, Wo, bo, x, out);
}